// Round 10
// baseline (1529.106 us; speedup 1.0000x reference)
//
#include <hip/hip_runtime.h>
#include <hip/hip_bf16.h>
#include <math.h>

#define NN 100000
#define NE 1600000
#define NFE 128
#define SCAN_NB 98        // ceil(NN/1024)
#define FILL_CHUNK 8192
#define FILL_NCHUNK 196   // ceil(NE/FILL_CHUNK)
#define FILL_BUCKET 12500 // NN/8 exactly

using f32x4 = __attribute__((ext_vector_type(4))) float;
using s16x8 = __attribute__((ext_vector_type(8))) short;
using s16x4 = __attribute__((ext_vector_type(4))) short;

__device__ __forceinline__ short bf16_rne(float x) {
  unsigned u = __float_as_uint(x);
  unsigned r = u + 0x7FFFu + ((u >> 16) & 1u);
  return (short)(r >> 16);
}
__device__ __forceinline__ float bf16_f(short s) {
  return __uint_as_float(((unsigned)(unsigned short)s) << 16);
}
__device__ __forceinline__ float leaky(float v) {
  return v >= 0.0f ? v : 0.02f * v;
}
__device__ __forceinline__ float4 fmax4(float4 a, float4 b) {
  return make_float4(fmaxf(a.x, b.x), fmaxf(a.y, b.y), fmaxf(a.z, b.z), fmaxf(a.w, b.w));
}

// ---------------- CSR build (once per call) ----------------

__global__ __launch_bounds__(256) void k_zero_i32(int* __restrict__ p, int n) {
  int i = blockIdx.x * blockDim.x + threadIdx.x;
  if (i < n) p[i] = 0;
}

__global__ __launch_bounds__(256) void k_hist_binned(const int* __restrict__ dst,
                                                     int* __restrict__ counts) {
  const int x = blockIdx.x & 7;
  const int k = blockIdx.x >> 3;
  const int lo = x * FILL_BUCKET, hi = lo + FILL_BUCKET;
  const int eend = min(NE, (k + 1) * FILL_CHUNK);
  for (int e = k * FILL_CHUNK + threadIdx.x; e < eend; e += 256) {
    int d = dst[e];
    if (d >= lo && d < hi) atomicAdd(&counts[d], 1);
  }
}

__global__ __launch_bounds__(256) void k_scan_sum(const int* __restrict__ counts,
                                                  int* __restrict__ bsum) {
  const int t = threadIdx.x;
  const int base = blockIdx.x * 1024 + t * 4;
  int4 c = make_int4(0, 0, 0, 0);
  if (base + 3 < NN) c = *(const int4*)(counts + base);
  else {
    if (base + 0 < NN) c.x = counts[base + 0];
    if (base + 1 < NN) c.y = counts[base + 1];
    if (base + 2 < NN) c.z = counts[base + 2];
  }
  int s = c.x + c.y + c.z + c.w;
#pragma unroll
  for (int off = 32; off; off >>= 1) s += __shfl_down(s, off, 64);
  __shared__ int ws[4];
  if ((t & 63) == 0) ws[t >> 6] = s;
  __syncthreads();
  if (t == 0) bsum[blockIdx.x] = ws[0] + ws[1] + ws[2] + ws[3];
}

__global__ __launch_bounds__(128) void k_scan_top(const int* __restrict__ bsum,
                                                  int* __restrict__ boff) {
  __shared__ int v[128];
  const int t = threadIdx.x;
  int mine = (t < SCAN_NB) ? bsum[t] : 0;
  v[t] = mine;
  __syncthreads();
  for (int off = 1; off < 128; off <<= 1) {
    int u = (t >= off) ? v[t - off] : 0;
    __syncthreads();
    v[t] += u;
    __syncthreads();
  }
  if (t < SCAN_NB) boff[t] = v[t] - mine;  // exclusive
}

__global__ __launch_bounds__(256) void k_scan_blk(const int* __restrict__ counts,
                                                  const int* __restrict__ boff,
                                                  int* __restrict__ row_ptr,
                                                  int* __restrict__ cursor) {
  __shared__ int part[256];
  const int t = threadIdx.x;
  const int base = blockIdx.x * 1024 + t * 4;
  int4 c = make_int4(0, 0, 0, 0);
  if (base + 3 < NN) c = *(const int4*)(counts + base);
  else {
    if (base + 0 < NN) c.x = counts[base + 0];
    if (base + 1 < NN) c.y = counts[base + 1];
    if (base + 2 < NN) c.z = counts[base + 2];
  }
  const int s = c.x + c.y + c.z + c.w;
  part[t] = s;
  __syncthreads();
  for (int off = 1; off < 256; off <<= 1) {
    int u = (t >= off) ? part[t - off] : 0;
    __syncthreads();
    part[t] += u;
    __syncthreads();
  }
  int excl = boff[blockIdx.x] + part[t] - s;
  int4 r;
  r.x = excl;
  r.y = r.x + c.x;
  r.z = r.y + c.y;
  r.w = r.z + c.z;
  const int4 z = make_int4(0, 0, 0, 0);
  if (base + 3 < NN) {
    *(int4*)(row_ptr + base) = r;
    *(int4*)(cursor + base) = z;
  } else {
    if (base + 0 < NN) { row_ptr[base + 0] = r.x; cursor[base + 0] = 0; }
    if (base + 1 < NN) { row_ptr[base + 1] = r.y; cursor[base + 1] = 0; }
    if (base + 2 < NN) { row_ptr[base + 2] = r.z; cursor[base + 2] = 0; }
  }
  if (blockIdx.x == 0 && t == 0) row_ptr[NN] = NE;
}

__global__ __launch_bounds__(256) void k_fill_binned(const int* __restrict__ src,
                                                     const int* __restrict__ dst,
                                                     const int* __restrict__ row_ptr,
                                                     int* __restrict__ cursor,
                                                     int* __restrict__ nbr) {
  const int x = blockIdx.x & 7;
  const int k = blockIdx.x >> 3;
  const int lo = x * FILL_BUCKET, hi = lo + FILL_BUCKET;
  const int eend = min(NE, (k + 1) * FILL_CHUNK);
  for (int e = k * FILL_CHUNK + threadIdx.x; e < eend; e += 256) {
    int d = dst[e];
    if (d >= lo && d < hi) {
      int p = atomicAdd(&cursor[d], 1);
      nbr[row_ptr[d] + p] = src[e];  // order within row nondeterministic; max is invariant
    }
  }
}

// ---------------- weight prep: f32 -> bf16 hi/lo ----------------

__global__ __launch_bounds__(256) void k_prep_w(const float* __restrict__ Wl,
                                                const float* __restrict__ Wr,
                                                short* __restrict__ wb) {
  int idx = blockIdx.x * 256 + threadIdx.x;
  if (idx >= 7 * 2 * 16384) return;
  int li = idx / 32768;
  int rem = idx % 32768;
  int seg = rem / 16384;
  int ok = rem % 16384;
  float v = seg ? Wr[li * 16384 + ok] : Wl[li * 16384 + ok];
  short hi = bf16_rne(v);
  short lo = bf16_rne(v - bf16_f(hi));
  short* base = wb + (size_t)li * 65536 + seg * 32768;
  base[ok] = hi;
  base[16384 + ok] = lo;
}

// ---------------- fused hidden layer: merged-row gather-max + split-bf16 MFMA ----------------
// hout = leaky( (max_{s in N(n)} hin[s]) @ Wl^T + bl + hin @ Wr^T )

__global__ __launch_bounds__(256) void k_layer_fused(const float* __restrict__ hin,
                                                     const int* __restrict__ row_ptr,
                                                     const int* __restrict__ nbr,
                                                     const short* __restrict__ wbl,
                                                     const float* __restrict__ bl,
                                                     float* __restrict__ hout) {
  // LDS: 0=agg hi, 1=agg lo, 2=hin hi, 3=hin lo; each 32 rows x 128 k bf16 (8KB)
  // XOR swizzle on byte offsets: off ^= (row&7)<<4 (write and read)
  __shared__ __align__(16) char smem[4 * 8192];
  const int t = threadIdx.x;
  const int base = blockIdx.x * 32;

  // --- stage hin tile (root branch) ---
  {
    char* dhi = smem + 2 * 8192;
    char* dlo = smem + 3 * 8192;
#pragma unroll
    for (int i = 0; i < 2; ++i) {
      int c = t + 256 * i;
      int row = c >> 4;
      int kc = (c & 15) * 8;
      const float4* g = (const float4*)(hin + (size_t)(base + row) * NFE + kc);
      float4 v0 = g[0], v1 = g[1];
      float f[8] = {v0.x, v0.y, v0.z, v0.w, v1.x, v1.y, v1.z, v1.w};
      s16x8 hv, lv;
#pragma unroll
      for (int j = 0; j < 8; ++j) {
        short h = bf16_rne(f[j]);
        hv[j] = h;
        lv[j] = bf16_rne(f[j] - bf16_f(h));
      }
      int off = row * 256 + kc * 2;
      off ^= (row & 7) << 4;
      *(s16x8*)(dhi + off) = hv;
      *(s16x8*)(dlo + off) = lv;
    }
  }

  // --- merged-row gather-max into the A tile (neighbor branch) ---
  // Group g owns 4 CONSECUTIVE rows; one loop over k<max(deg) keeps 4 index
  // loads + 4 dwordx4 gathers in flight per lane (vs 1 row's worth before).
  // Clamped re-loads of a finished row's last neighbor are L1-hot.
  {
    char* ahi = smem;
    char* alo = smem + 8192;
    const int grp = t >> 5;        // 8 groups of 32 lanes
    const int lg = t & 31;
    const int c4 = lg << 2;        // 4 contiguous channels
    const int n0 = base + grp * 4;
    const int p0 = row_ptr[n0 + 0];
    const int p1 = row_ptr[n0 + 1];
    const int p2 = row_ptr[n0 + 2];
    const int p3 = row_ptr[n0 + 3];
    const int p4 = row_ptr[n0 + 4];
    const int d0 = p1 - p0, d1 = p2 - p1, d2 = p3 - p2, d3 = p4 - p3;
    const int dmax = max(max(d0, d1), max(d2, d3));
    const float NI = __int_as_float(0xFF800000);
    float4 m0 = make_float4(NI, NI, NI, NI), m1 = m0, m2 = m0, m3 = m0;
    for (int k = 0; k < dmax; ++k) {
      int i0 = max(p0 + min(k, d0 - 1), 0);
      int i1 = max(p1 + min(k, d1 - 1), 0);
      int i2 = max(p2 + min(k, d2 - 1), 0);
      int i3 = max(p3 + min(k, d3 - 1), 0);
      int s0 = nbr[i0], s1 = nbr[i1], s2 = nbr[i2], s3 = nbr[i3];
      float4 v0 = *(const float4*)(hin + (size_t)s0 * NFE + c4);
      float4 v1 = *(const float4*)(hin + (size_t)s1 * NFE + c4);
      float4 v2 = *(const float4*)(hin + (size_t)s2 * NFE + c4);
      float4 v3 = *(const float4*)(hin + (size_t)s3 * NFE + c4);
      m0 = (k < d0) ? fmax4(m0, v0) : m0;
      m1 = (k < d1) ? fmax4(m1, v1) : m1;
      m2 = (k < d2) ? fmax4(m2, v2) : m2;
      m3 = (k < d3) ? fmax4(m3, v3) : m3;
    }
    if (d0 == 0) m0 = make_float4(0.f, 0.f, 0.f, 0.f);
    if (d1 == 0) m1 = make_float4(0.f, 0.f, 0.f, 0.f);
    if (d2 == 0) m2 = make_float4(0.f, 0.f, 0.f, 0.f);
    if (d3 == 0) m3 = make_float4(0.f, 0.f, 0.f, 0.f);
    float4 ms[4] = {m0, m1, m2, m3};
#pragma unroll
    for (int ni = 0; ni < 4; ++ni) {
      const int r = grp * 4 + ni;
      float f[4] = {ms[ni].x, ms[ni].y, ms[ni].z, ms[ni].w};
      s16x4 hv, lv;
#pragma unroll
      for (int q = 0; q < 4; ++q) {
        short h = bf16_rne(f[q]);
        hv[q] = h;
        lv[q] = bf16_rne(f[q] - bf16_f(h));
      }
      int off = r * 256 + c4 * 2;
      off ^= (r & 7) << 4;
      *(s16x4*)(ahi + off) = hv;
      *(s16x4*)(alo + off) = lv;
    }
  }
  __syncthreads();

  // --- split-bf16 MFMA: Ahi*Whi + Ahi*Wlo + Alo*Whi per branch ---
  const int w = t >> 6;
  const int l = t & 63;
  const int lr = l & 15;
  const int lk = (l >> 4) * 8;

  f32x4 acc[2][2] = {};

#pragma unroll
  for (int seg = 0; seg < 2; ++seg) {
    const char* ahi = smem + (seg * 2 + 0) * 8192;
    const char* alo = smem + (seg * 2 + 1) * 8192;
    const short* bhb = wbl + seg * 32768;
    const short* blb = wbl + seg * 32768 + 16384;
#pragma unroll
    for (int ks = 0; ks < 4; ++ks) {
      const int k0 = ks * 32;
      int offa0 = (lr) * 256 + (k0 + lk) * 2;      offa0 ^= ((lr) & 7) << 4;
      int offa1 = (16 + lr) * 256 + (k0 + lk) * 2; offa1 ^= ((16 + lr) & 7) << 4;
      s16x8 ah0 = *(const s16x8*)(ahi + offa0);
      s16x8 ah1 = *(const s16x8*)(ahi + offa1);
      s16x8 al0 = *(const s16x8*)(alo + offa0);
      s16x8 al1 = *(const s16x8*)(alo + offa1);
#pragma unroll
      for (int ct = 0; ct < 2; ++ct) {
        const int col = w * 32 + ct * 16 + lr;
        const s16x8 bh = *(const s16x8*)(bhb + col * 128 + k0 + lk);
        const s16x8 bl_ = *(const s16x8*)(blb + col * 128 + k0 + lk);
        acc[0][ct] = __builtin_amdgcn_mfma_f32_16x16x32_bf16(ah0, bh, acc[0][ct], 0, 0, 0);
        acc[1][ct] = __builtin_amdgcn_mfma_f32_16x16x32_bf16(ah1, bh, acc[1][ct], 0, 0, 0);
        acc[0][ct] = __builtin_amdgcn_mfma_f32_16x16x32_bf16(ah0, bl_, acc[0][ct], 0, 0, 0);
        acc[1][ct] = __builtin_amdgcn_mfma_f32_16x16x32_bf16(ah1, bl_, acc[1][ct], 0, 0, 0);
        acc[0][ct] = __builtin_amdgcn_mfma_f32_16x16x32_bf16(al0, bh, acc[0][ct], 0, 0, 0);
        acc[1][ct] = __builtin_amdgcn_mfma_f32_16x16x32_bf16(al1, bh, acc[1][ct], 0, 0, 0);
      }
    }
  }

  // epilogue: bias + leaky; C layout: col = lane&15, row = (lane>>4)*4 + reg
  const float bias0 = bl[w * 32 + lr];
  const float bias1 = bl[w * 32 + 16 + lr];
#pragma unroll
  for (int rt = 0; rt < 2; ++rt) {
#pragma unroll
    for (int r = 0; r < 4; ++r) {
      int node = base + 16 * rt + (l >> 4) * 4 + r;
      float* o = hout + (size_t)node * NFE + w * 32;
      o[lr]      = leaky(acc[rt][0][r] + bias0);
      o[16 + lr] = leaky(acc[rt][1][r] + bias1);
    }
  }
}

// ---------------- fused output layer: gather-max + tiny GEMV + tanh ----------------

__global__ __launch_bounds__(256) void k_final_fused(const float* __restrict__ h,
                                                     const int* __restrict__ row_ptr,
                                                     const int* __restrict__ nbr,
                                                     const float* __restrict__ Wlo,
                                                     const float* __restrict__ blo,
                                                     const float* __restrict__ Wro,
                                                     float* __restrict__ out) {
  const int wave = threadIdx.x >> 6;
  const int lane = threadIdx.x & 63;
  const int n = blockIdx.x * 4 + wave;
  if (n >= NN) return;
  const int c2 = lane * 2;
  const int start = row_ptr[n], end = row_ptr[n + 1];
  const float NI = __int_as_float(0xFF800000);
  float ax = NI, ay = NI;
  int j = start;
  for (; j + 4 <= end; j += 4) {
    int s0 = nbr[j], s1 = nbr[j + 1], s2 = nbr[j + 2], s3 = nbr[j + 3];
    float2 v0 = *(const float2*)(h + (size_t)s0 * NFE + c2);
    float2 v1 = *(const float2*)(h + (size_t)s1 * NFE + c2);
    float2 v2 = *(const float2*)(h + (size_t)s2 * NFE + c2);
    float2 v3 = *(const float2*)(h + (size_t)s3 * NFE + c2);
    ax = fmaxf(ax, fmaxf(fmaxf(v0.x, v1.x), fmaxf(v2.x, v3.x)));
    ay = fmaxf(ay, fmaxf(fmaxf(v0.y, v1.y), fmaxf(v2.y, v3.y)));
  }
  for (; j < end; ++j) {
    float2 v = *(const float2*)(h + (size_t)nbr[j] * NFE + c2);
    ax = fmaxf(ax, v.x);
    ay = fmaxf(ay, v.y);
  }
  if (start == end) { ax = 0.f; ay = 0.f; }
  const float2 hv = *(const float2*)(h + (size_t)n * NFE + c2);
  float p[3];
#pragma unroll
  for (int o = 0; o < 3; ++o) {
    const float2 wl = *(const float2*)(Wlo + o * NFE + c2);
    const float2 wr = *(const float2*)(Wro + o * NFE + c2);
    p[o] = ax * wl.x + ay * wl.y + hv.x * wr.x + hv.y * wr.y;
#pragma unroll
    for (int off = 32; off; off >>= 1) p[o] += __shfl_down(p[o], off, 64);
  }
  if (lane == 0) {
#pragma unroll
    for (int o = 0; o < 3; ++o)
      out[(size_t)n * 3 + o] = tanhf(p[o] + blo[o]) * 0.5f;
  }
}

// ---------------- launch ----------------

extern "C" void kernel_launch(void* const* d_in, const int* in_sizes, int n_in,
                              void* d_out, int out_size, void* d_ws, size_t ws_size,
                              hipStream_t stream) {
  const float* x   = (const float*)d_in[0];
  const int*   ei  = (const int*)d_in[1];
  const float* Wl  = (const float*)d_in[2];
  const float* bl  = (const float*)d_in[3];
  const float* Wr  = (const float*)d_in[4];
  const float* Wlo = (const float*)d_in[5];
  const float* blo = (const float*)d_in[6];
  const float* Wro = (const float*)d_in[7];
  float* out = (float*)d_out;

  const int* src = ei;
  const int* dst = ei + NE;

  char* ws = (char*)d_ws;
  size_t off = 0;
  auto alloc = [&](size_t bytes) { void* p = ws + off; off = (off + bytes + 255) & ~(size_t)255; return p; };
  int* counts  = (int*)alloc(sizeof(int) * NN);
  int* cursor  = (int*)alloc(sizeof(int) * NN);
  int* row_ptr = (int*)alloc(sizeof(int) * (NN + 1));
  int* nbr     = (int*)alloc(sizeof(int) * NE);
  int* bsum    = (int*)alloc(sizeof(int) * 128);
  int* boff    = (int*)alloc(sizeof(int) * 128);
  short* wb    = (short*)alloc(sizeof(short) * 7 * 65536);
  const size_t hbytes = (size_t)NN * NFE * sizeof(float);
  float* hA  = (float*)alloc(hbytes);
  float* hB  = (float*)alloc(hbytes);

  k_prep_w<<<(7 * 32768 + 255) / 256, 256, 0, stream>>>(Wl, Wr, wb);
  k_zero_i32<<<(NN + 255) / 256, 256, 0, stream>>>(counts, NN);
  k_hist_binned<<<8 * FILL_NCHUNK, 256, 0, stream>>>(dst, counts);
  k_scan_sum<<<SCAN_NB, 256, 0, stream>>>(counts, bsum);
  k_scan_top<<<1, 128, 0, stream>>>(bsum, boff);
  k_scan_blk<<<SCAN_NB, 256, 0, stream>>>(counts, boff, row_ptr, cursor);
  k_fill_binned<<<8 * FILL_NCHUNK, 256, 0, stream>>>(src, dst, row_ptr, cursor, nbr);

  const float* hin = x;
  float* bufs[2] = {hA, hB};
  for (int i = 0; i < 7; ++i) {
    float* hout = bufs[i & 1];
    k_layer_fused<<<NN / 32, 256, 0, stream>>>(hin, row_ptr, nbr,
                                               wb + (size_t)i * 65536,
                                               bl + (size_t)i * NFE, hout);
    hin = hout;
  }

  k_final_fused<<<(NN + 3) / 4, 256, 0, stream>>>(hin, row_ptr, nbr, Wlo, blo, Wro, out);
}

// Round 11
// 1333.813 us; speedup vs baseline: 1.1464x; 1.1464x over previous
//
#include <hip/hip_runtime.h>
#include <hip/hip_bf16.h>
#include <math.h>

#define NN 100000
#define NE 1600000
#define NFE 128
#define SCAN_NB 98        // ceil(NN/1024)
#define FILL_CHUNK 8192
#define FILL_NCHUNK 196   // ceil(NE/FILL_CHUNK)
#define FILL_BUCKET 12500 // NN/8 exactly

using f32x4 = __attribute__((ext_vector_type(4))) float;
using s16x8 = __attribute__((ext_vector_type(8))) short;
using s16x4 = __attribute__((ext_vector_type(4))) short;

__device__ __forceinline__ short bf16_rne(float x) {
  unsigned u = __float_as_uint(x);
  unsigned r = u + 0x7FFFu + ((u >> 16) & 1u);
  return (short)(r >> 16);
}
__device__ __forceinline__ float bf16_f(short s) {
  return __uint_as_float(((unsigned)(unsigned short)s) << 16);
}
__device__ __forceinline__ float leaky(float v) {
  return v >= 0.0f ? v : 0.02f * v;
}
__device__ __forceinline__ float4 fmax4(float4 a, float4 b) {
  return make_float4(fmaxf(a.x, b.x), fmaxf(a.y, b.y), fmaxf(a.z, b.z), fmaxf(a.w, b.w));
}

// ---------------- CSR build (once per call) ----------------

__global__ __launch_bounds__(256) void k_zero_i32(int* __restrict__ p, int n) {
  int i = blockIdx.x * blockDim.x + threadIdx.x;
  if (i < n) p[i] = 0;
}

__global__ __launch_bounds__(256) void k_hist_binned(const int* __restrict__ dst,
                                                     int* __restrict__ counts) {
  const int x = blockIdx.x & 7;
  const int k = blockIdx.x >> 3;
  const int lo = x * FILL_BUCKET, hi = lo + FILL_BUCKET;
  const int eend = min(NE, (k + 1) * FILL_CHUNK);
  for (int e = k * FILL_CHUNK + threadIdx.x; e < eend; e += 256) {
    int d = dst[e];
    if (d >= lo && d < hi) atomicAdd(&counts[d], 1);
  }
}

__global__ __launch_bounds__(256) void k_scan_sum(const int* __restrict__ counts,
                                                  int* __restrict__ bsum) {
  const int t = threadIdx.x;
  const int base = blockIdx.x * 1024 + t * 4;
  int4 c = make_int4(0, 0, 0, 0);
  if (base + 3 < NN) c = *(const int4*)(counts + base);
  else {
    if (base + 0 < NN) c.x = counts[base + 0];
    if (base + 1 < NN) c.y = counts[base + 1];
    if (base + 2 < NN) c.z = counts[base + 2];
  }
  int s = c.x + c.y + c.z + c.w;
#pragma unroll
  for (int off = 32; off; off >>= 1) s += __shfl_down(s, off, 64);
  __shared__ int ws[4];
  if ((t & 63) == 0) ws[t >> 6] = s;
  __syncthreads();
  if (t == 0) bsum[blockIdx.x] = ws[0] + ws[1] + ws[2] + ws[3];
}

__global__ __launch_bounds__(128) void k_scan_top(const int* __restrict__ bsum,
                                                  int* __restrict__ boff) {
  __shared__ int v[128];
  const int t = threadIdx.x;
  int mine = (t < SCAN_NB) ? bsum[t] : 0;
  v[t] = mine;
  __syncthreads();
  for (int off = 1; off < 128; off <<= 1) {
    int u = (t >= off) ? v[t - off] : 0;
    __syncthreads();
    v[t] += u;
    __syncthreads();
  }
  if (t < SCAN_NB) boff[t] = v[t] - mine;  // exclusive
}

__global__ __launch_bounds__(256) void k_scan_blk(const int* __restrict__ counts,
                                                  const int* __restrict__ boff,
                                                  int* __restrict__ row_ptr,
                                                  int* __restrict__ cursor) {
  __shared__ int part[256];
  const int t = threadIdx.x;
  const int base = blockIdx.x * 1024 + t * 4;
  int4 c = make_int4(0, 0, 0, 0);
  if (base + 3 < NN) c = *(const int4*)(counts + base);
  else {
    if (base + 0 < NN) c.x = counts[base + 0];
    if (base + 1 < NN) c.y = counts[base + 1];
    if (base + 2 < NN) c.z = counts[base + 2];
  }
  const int s = c.x + c.y + c.z + c.w;
  part[t] = s;
  __syncthreads();
  for (int off = 1; off < 256; off <<= 1) {
    int u = (t >= off) ? part[t - off] : 0;
    __syncthreads();
    part[t] += u;
    __syncthreads();
  }
  int excl = boff[blockIdx.x] + part[t] - s;
  int4 r;
  r.x = excl;
  r.y = r.x + c.x;
  r.z = r.y + c.y;
  r.w = r.z + c.z;
  const int4 z = make_int4(0, 0, 0, 0);
  if (base + 3 < NN) {
    *(int4*)(row_ptr + base) = r;
    *(int4*)(cursor + base) = z;
  } else {
    if (base + 0 < NN) { row_ptr[base + 0] = r.x; cursor[base + 0] = 0; }
    if (base + 1 < NN) { row_ptr[base + 1] = r.y; cursor[base + 1] = 0; }
    if (base + 2 < NN) { row_ptr[base + 2] = r.z; cursor[base + 2] = 0; }
  }
  if (blockIdx.x == 0 && t == 0) row_ptr[NN] = NE;
}

__global__ __launch_bounds__(256) void k_fill_binned(const int* __restrict__ src,
                                                     const int* __restrict__ dst,
                                                     const int* __restrict__ row_ptr,
                                                     int* __restrict__ cursor,
                                                     int* __restrict__ nbr) {
  const int x = blockIdx.x & 7;
  const int k = blockIdx.x >> 3;
  const int lo = x * FILL_BUCKET, hi = lo + FILL_BUCKET;
  const int eend = min(NE, (k + 1) * FILL_CHUNK);
  for (int e = k * FILL_CHUNK + threadIdx.x; e < eend; e += 256) {
    int d = dst[e];
    if (d >= lo && d < hi) {
      int p = atomicAdd(&cursor[d], 1);
      nbr[row_ptr[d] + p] = src[e];  // order within row nondeterministic; max is invariant
    }
  }
}

// ---------------- weight prep: f32 -> bf16 hi/lo ----------------

__global__ __launch_bounds__(256) void k_prep_w(const float* __restrict__ Wl,
                                                const float* __restrict__ Wr,
                                                short* __restrict__ wb) {
  int idx = blockIdx.x * 256 + threadIdx.x;
  if (idx >= 7 * 2 * 16384) return;
  int li = idx / 32768;
  int rem = idx % 32768;
  int seg = rem / 16384;
  int ok = rem % 16384;
  float v = seg ? Wr[li * 16384 + ok] : Wl[li * 16384 + ok];
  short hi = bf16_rne(v);
  short lo = bf16_rne(v - bf16_f(hi));
  short* base = wb + (size_t)li * 65536 + seg * 32768;
  base[ok] = hi;
  base[16384 + ok] = lo;
}

// ---------------- fused hidden layer: 512-thread, 32-node tile ----------------
// hout = leaky( (max_{s in N(n)} hin[s]) @ Wl^T + bl + hin @ Wr^T )
// 8 waves/block, 32KB LDS -> 4 blocks/CU = 32 waves/CU (HW cap).
// Gather: 16 groups x 2 rows (r9's serial-row form, shorter chain).
// MFMA: each wave owns 16 output cols (48 MFMA).

__global__ __launch_bounds__(512, 8) void k_layer_fused(const float* __restrict__ hin,
                                                        const int* __restrict__ row_ptr,
                                                        const int* __restrict__ nbr,
                                                        const short* __restrict__ wbl,
                                                        const float* __restrict__ bl,
                                                        float* __restrict__ hout) {
  // LDS: 0=agg hi, 1=agg lo, 2=hin hi, 3=hin lo; each 32 rows x 128 k bf16 (8KB)
  // XOR swizzle on byte offsets: off ^= (row&7)<<4 (write and read)
  __shared__ __align__(16) char smem[4 * 8192];
  const int t = threadIdx.x;
  const int base = blockIdx.x * 32;

  // --- stage hin tile (root branch): one 8-float chunk per thread ---
  {
    char* dhi = smem + 2 * 8192;
    char* dlo = smem + 3 * 8192;
    int row = t >> 4;             // 32 rows x 16 chunks = 512
    int kc = (t & 15) * 8;
    const float4* g = (const float4*)(hin + (size_t)(base + row) * NFE + kc);
    float4 v0 = g[0], v1 = g[1];
    float f[8] = {v0.x, v0.y, v0.z, v0.w, v1.x, v1.y, v1.z, v1.w};
    s16x8 hv, lv;
#pragma unroll
    for (int j = 0; j < 8; ++j) {
      short h = bf16_rne(f[j]);
      hv[j] = h;
      lv[j] = bf16_rne(f[j] - bf16_f(h));
    }
    int off = row * 256 + kc * 2;
    off ^= (row & 7) << 4;
    *(s16x8*)(dhi + off) = hv;
    *(s16x8*)(dlo + off) = lv;
  }

  // --- gather-max into the A tile: 16 groups of 32 lanes, 2 rows each ---
  {
    char* ahi = smem;
    char* alo = smem + 8192;
    const int grp = t >> 5;        // 0..15
    const int lg = t & 31;
    const int c4 = lg << 2;        // 4 contiguous channels
    const float NI = __int_as_float(0xFF800000);
#pragma unroll
    for (int ni = 0; ni < 2; ++ni) {
      const int r = grp * 2 + ni;  // in-block row
      const int n = base + r;
      const int start = row_ptr[n], end = row_ptr[n + 1];
      float4 acc = make_float4(NI, NI, NI, NI);
      int j = start;
      for (; j + 4 <= end; j += 4) {
        int s0 = nbr[j], s1 = nbr[j + 1], s2 = nbr[j + 2], s3 = nbr[j + 3];
        float4 v0 = *(const float4*)(hin + (size_t)s0 * NFE + c4);
        float4 v1 = *(const float4*)(hin + (size_t)s1 * NFE + c4);
        float4 v2 = *(const float4*)(hin + (size_t)s2 * NFE + c4);
        float4 v3 = *(const float4*)(hin + (size_t)s3 * NFE + c4);
        acc = fmax4(acc, fmax4(fmax4(v0, v1), fmax4(v2, v3)));
      }
      for (; j < end; ++j) {
        int s = nbr[j];
        acc = fmax4(acc, *(const float4*)(hin + (size_t)s * NFE + c4));
      }
      if (start == end) acc = make_float4(0.f, 0.f, 0.f, 0.f);
      float f[4] = {acc.x, acc.y, acc.z, acc.w};
      s16x4 hv, lv;
#pragma unroll
      for (int q = 0; q < 4; ++q) {
        short h = bf16_rne(f[q]);
        hv[q] = h;
        lv[q] = bf16_rne(f[q] - bf16_f(h));
      }
      int off = r * 256 + c4 * 2;
      off ^= (r & 7) << 4;
      *(s16x4*)(ahi + off) = hv;
      *(s16x4*)(alo + off) = lv;
    }
  }
  __syncthreads();

  // --- split-bf16 MFMA: Ahi*Whi + Ahi*Wlo + Alo*Whi per branch ---
  const int w = t >> 6;        // wave id 0..7: cols 16w..16w+15
  const int l = t & 63;
  const int lr = l & 15;
  const int lk = (l >> 4) * 8;

  f32x4 acc[2] = {};           // [row tile]

#pragma unroll
  for (int seg = 0; seg < 2; ++seg) {
    const char* ahi = smem + (seg * 2 + 0) * 8192;
    const char* alo = smem + (seg * 2 + 1) * 8192;
    const short* bhb = wbl + seg * 32768;
    const short* blb = wbl + seg * 32768 + 16384;
#pragma unroll
    for (int ks = 0; ks < 4; ++ks) {
      const int k0 = ks * 32;
      int offa0 = (lr) * 256 + (k0 + lk) * 2;      offa0 ^= ((lr) & 7) << 4;
      int offa1 = (16 + lr) * 256 + (k0 + lk) * 2; offa1 ^= ((16 + lr) & 7) << 4;
      s16x8 ah0 = *(const s16x8*)(ahi + offa0);
      s16x8 ah1 = *(const s16x8*)(ahi + offa1);
      s16x8 al0 = *(const s16x8*)(alo + offa0);
      s16x8 al1 = *(const s16x8*)(alo + offa1);
      const int col = w * 16 + lr;
      const s16x8 bh = *(const s16x8*)(bhb + col * 128 + k0 + lk);
      const s16x8 bl_ = *(const s16x8*)(blb + col * 128 + k0 + lk);
      acc[0] = __builtin_amdgcn_mfma_f32_16x16x32_bf16(ah0, bh, acc[0], 0, 0, 0);
      acc[1] = __builtin_amdgcn_mfma_f32_16x16x32_bf16(ah1, bh, acc[1], 0, 0, 0);
      acc[0] = __builtin_amdgcn_mfma_f32_16x16x32_bf16(ah0, bl_, acc[0], 0, 0, 0);
      acc[1] = __builtin_amdgcn_mfma_f32_16x16x32_bf16(ah1, bl_, acc[1], 0, 0, 0);
      acc[0] = __builtin_amdgcn_mfma_f32_16x16x32_bf16(al0, bh, acc[0], 0, 0, 0);
      acc[1] = __builtin_amdgcn_mfma_f32_16x16x32_bf16(al1, bh, acc[1], 0, 0, 0);
    }
  }

  // epilogue: bias + leaky; C layout: col = lane&15, row = (lane>>4)*4 + reg
  const float bias0 = bl[w * 16 + lr];
#pragma unroll
  for (int rt = 0; rt < 2; ++rt) {
#pragma unroll
    for (int r = 0; r < 4; ++r) {
      int node = base + 16 * rt + (l >> 4) * 4 + r;
      float* o = hout + (size_t)node * NFE + w * 16;
      o[lr] = leaky(acc[rt][r] + bias0);
    }
  }
}

// ---------------- fused output layer: gather-max + tiny GEMV + tanh ----------------

__global__ __launch_bounds__(256) void k_final_fused(const float* __restrict__ h,
                                                     const int* __restrict__ row_ptr,
                                                     const int* __restrict__ nbr,
                                                     const float* __restrict__ Wlo,
                                                     const float* __restrict__ blo,
                                                     const float* __restrict__ Wro,
                                                     float* __restrict__ out) {
  const int wave = threadIdx.x >> 6;
  const int lane = threadIdx.x & 63;
  const int n = blockIdx.x * 4 + wave;
  if (n >= NN) return;
  const int c2 = lane * 2;
  const int start = row_ptr[n], end = row_ptr[n + 1];
  const float NI = __int_as_float(0xFF800000);
  float ax = NI, ay = NI;
  int j = start;
  for (; j + 4 <= end; j += 4) {
    int s0 = nbr[j], s1 = nbr[j + 1], s2 = nbr[j + 2], s3 = nbr[j + 3];
    float2 v0 = *(const float2*)(h + (size_t)s0 * NFE + c2);
    float2 v1 = *(const float2*)(h + (size_t)s1 * NFE + c2);
    float2 v2 = *(const float2*)(h + (size_t)s2 * NFE + c2);
    float2 v3 = *(const float2*)(h + (size_t)s3 * NFE + c2);
    ax = fmaxf(ax, fmaxf(fmaxf(v0.x, v1.x), fmaxf(v2.x, v3.x)));
    ay = fmaxf(ay, fmaxf(fmaxf(v0.y, v1.y), fmaxf(v2.y, v3.y)));
  }
  for (; j < end; ++j) {
    float2 v = *(const float2*)(h + (size_t)nbr[j] * NFE + c2);
    ax = fmaxf(ax, v.x);
    ay = fmaxf(ay, v.y);
  }
  if (start == end) { ax = 0.f; ay = 0.f; }
  const float2 hv = *(const float2*)(h + (size_t)n * NFE + c2);
  float p[3];
#pragma unroll
  for (int o = 0; o < 3; ++o) {
    const float2 wl = *(const float2*)(Wlo + o * NFE + c2);
    const float2 wr = *(const float2*)(Wro + o * NFE + c2);
    p[o] = ax * wl.x + ay * wl.y + hv.x * wr.x + hv.y * wr.y;
#pragma unroll
    for (int off = 32; off; off >>= 1) p[o] += __shfl_down(p[o], off, 64);
  }
  if (lane == 0) {
#pragma unroll
    for (int o = 0; o < 3; ++o)
      out[(size_t)n * 3 + o] = tanhf(p[o] + blo[o]) * 0.5f;
  }
}

// ---------------- launch ----------------

extern "C" void kernel_launch(void* const* d_in, const int* in_sizes, int n_in,
                              void* d_out, int out_size, void* d_ws, size_t ws_size,
                              hipStream_t stream) {
  const float* x   = (const float*)d_in[0];
  const int*   ei  = (const int*)d_in[1];
  const float* Wl  = (const float*)d_in[2];
  const float* bl  = (const float*)d_in[3];
  const float* Wr  = (const float*)d_in[4];
  const float* Wlo = (const float*)d_in[5];
  const float* blo = (const float*)d_in[6];
  const float* Wro = (const float*)d_in[7];
  float* out = (float*)d_out;

  const int* src = ei;
  const int* dst = ei + NE;

  char* ws = (char*)d_ws;
  size_t off = 0;
  auto alloc = [&](size_t bytes) { void* p = ws + off; off = (off + bytes + 255) & ~(size_t)255; return p; };
  int* counts  = (int*)alloc(sizeof(int) * NN);
  int* cursor  = (int*)alloc(sizeof(int) * NN);
  int* row_ptr = (int*)alloc(sizeof(int) * (NN + 1));
  int* nbr     = (int*)alloc(sizeof(int) * NE);
  int* bsum    = (int*)alloc(sizeof(int) * 128);
  int* boff    = (int*)alloc(sizeof(int) * 128);
  short* wb    = (short*)alloc(sizeof(short) * 7 * 65536);
  const size_t hbytes = (size_t)NN * NFE * sizeof(float);
  float* hA  = (float*)alloc(hbytes);
  float* hB  = (float*)alloc(hbytes);

  k_prep_w<<<(7 * 32768 + 255) / 256, 256, 0, stream>>>(Wl, Wr, wb);
  k_zero_i32<<<(NN + 255) / 256, 256, 0, stream>>>(counts, NN);
  k_hist_binned<<<8 * FILL_NCHUNK, 256, 0, stream>>>(dst, counts);
  k_scan_sum<<<SCAN_NB, 256, 0, stream>>>(counts, bsum);
  k_scan_top<<<1, 128, 0, stream>>>(bsum, boff);
  k_scan_blk<<<SCAN_NB, 256, 0, stream>>>(counts, boff, row_ptr, cursor);
  k_fill_binned<<<8 * FILL_NCHUNK, 256, 0, stream>>>(src, dst, row_ptr, cursor, nbr);

  const float* hin = x;
  float* bufs[2] = {hA, hB};
  for (int i = 0; i < 7; ++i) {
    float* hout = bufs[i & 1];
    k_layer_fused<<<NN / 32, 512, 0, stream>>>(hin, row_ptr, nbr,
                                               wb + (size_t)i * 65536,
                                               bl + (size_t)i * NFE, hout);
    hin = hout;
  }

  k_final_fused<<<(NN + 3) / 4, 256, 0, stream>>>(hin, row_ptr, nbr, Wlo, blo, Wro, out);
}

// Round 12
// 1255.938 us; speedup vs baseline: 1.2175x; 1.0620x over previous
//
#include <hip/hip_runtime.h>
#include <hip/hip_bf16.h>
#include <math.h>

#define NN 100000
#define NE 1600000
#define NFE 128
#define SCAN_NB 98        // ceil(NN/1024)
#define FILL_CHUNK 8192
#define FILL_NCHUNK 196   // ceil(NE/FILL_CHUNK)
#define FILL_BUCKET 12500 // NN/8 exactly

using f32x4 = __attribute__((ext_vector_type(4))) float;
using s16x8 = __attribute__((ext_vector_type(8))) short;
using s16x4 = __attribute__((ext_vector_type(4))) short;

__device__ __forceinline__ short bf16_rne(float x) {
  unsigned u = __float_as_uint(x);
  unsigned r = u + 0x7FFFu + ((u >> 16) & 1u);
  return (short)(r >> 16);
}
__device__ __forceinline__ float bf16_f(short s) {
  return __uint_as_float(((unsigned)(unsigned short)s) << 16);
}
__device__ __forceinline__ float leaky(float v) {
  return v >= 0.0f ? v : 0.02f * v;
}
__device__ __forceinline__ float4 fmax4(float4 a, float4 b) {
  return make_float4(fmaxf(a.x, b.x), fmaxf(a.y, b.y), fmaxf(a.z, b.z), fmaxf(a.w, b.w));
}

// ---------------- CSR build (once per call) ----------------

__global__ __launch_bounds__(256) void k_zero_i32(int* __restrict__ p, int n) {
  int i = blockIdx.x * blockDim.x + threadIdx.x;
  if (i < n) p[i] = 0;
}

__global__ __launch_bounds__(256) void k_hist_binned(const int* __restrict__ dst,
                                                     int* __restrict__ counts) {
  const int x = blockIdx.x & 7;
  const int k = blockIdx.x >> 3;
  const int lo = x * FILL_BUCKET, hi = lo + FILL_BUCKET;
  const int eend = min(NE, (k + 1) * FILL_CHUNK);
  for (int e = k * FILL_CHUNK + threadIdx.x; e < eend; e += 256) {
    int d = dst[e];
    if (d >= lo && d < hi) atomicAdd(&counts[d], 1);
  }
}

__global__ __launch_bounds__(256) void k_scan_sum(const int* __restrict__ counts,
                                                  int* __restrict__ bsum) {
  const int t = threadIdx.x;
  const int base = blockIdx.x * 1024 + t * 4;
  int4 c = make_int4(0, 0, 0, 0);
  if (base + 3 < NN) c = *(const int4*)(counts + base);
  else {
    if (base + 0 < NN) c.x = counts[base + 0];
    if (base + 1 < NN) c.y = counts[base + 1];
    if (base + 2 < NN) c.z = counts[base + 2];
  }
  int s = c.x + c.y + c.z + c.w;
#pragma unroll
  for (int off = 32; off; off >>= 1) s += __shfl_down(s, off, 64);
  __shared__ int ws[4];
  if ((t & 63) == 0) ws[t >> 6] = s;
  __syncthreads();
  if (t == 0) bsum[blockIdx.x] = ws[0] + ws[1] + ws[2] + ws[3];
}

__global__ __launch_bounds__(128) void k_scan_top(const int* __restrict__ bsum,
                                                  int* __restrict__ boff) {
  __shared__ int v[128];
  const int t = threadIdx.x;
  int mine = (t < SCAN_NB) ? bsum[t] : 0;
  v[t] = mine;
  __syncthreads();
  for (int off = 1; off < 128; off <<= 1) {
    int u = (t >= off) ? v[t - off] : 0;
    __syncthreads();
    v[t] += u;
    __syncthreads();
  }
  if (t < SCAN_NB) boff[t] = v[t] - mine;  // exclusive
}

__global__ __launch_bounds__(256) void k_scan_blk(const int* __restrict__ counts,
                                                  const int* __restrict__ boff,
                                                  int* __restrict__ row_ptr,
                                                  int* __restrict__ cursor) {
  __shared__ int part[256];
  const int t = threadIdx.x;
  const int base = blockIdx.x * 1024 + t * 4;
  int4 c = make_int4(0, 0, 0, 0);
  if (base + 3 < NN) c = *(const int4*)(counts + base);
  else {
    if (base + 0 < NN) c.x = counts[base + 0];
    if (base + 1 < NN) c.y = counts[base + 1];
    if (base + 2 < NN) c.z = counts[base + 2];
  }
  const int s = c.x + c.y + c.z + c.w;
  part[t] = s;
  __syncthreads();
  for (int off = 1; off < 256; off <<= 1) {
    int u = (t >= off) ? part[t - off] : 0;
    __syncthreads();
    part[t] += u;
    __syncthreads();
  }
  int excl = boff[blockIdx.x] + part[t] - s;
  int4 r;
  r.x = excl;
  r.y = r.x + c.x;
  r.z = r.y + c.y;
  r.w = r.z + c.z;
  const int4 z = make_int4(0, 0, 0, 0);
  if (base + 3 < NN) {
    *(int4*)(row_ptr + base) = r;
    *(int4*)(cursor + base) = z;
  } else {
    if (base + 0 < NN) { row_ptr[base + 0] = r.x; cursor[base + 0] = 0; }
    if (base + 1 < NN) { row_ptr[base + 1] = r.y; cursor[base + 1] = 0; }
    if (base + 2 < NN) { row_ptr[base + 2] = r.z; cursor[base + 2] = 0; }
  }
  if (blockIdx.x == 0 && t == 0) row_ptr[NN] = NE;
}

__global__ __launch_bounds__(256) void k_fill_binned(const int* __restrict__ src,
                                                     const int* __restrict__ dst,
                                                     const int* __restrict__ row_ptr,
                                                     int* __restrict__ cursor,
                                                     int* __restrict__ nbr) {
  const int x = blockIdx.x & 7;
  const int k = blockIdx.x >> 3;
  const int lo = x * FILL_BUCKET, hi = lo + FILL_BUCKET;
  const int eend = min(NE, (k + 1) * FILL_CHUNK);
  for (int e = k * FILL_CHUNK + threadIdx.x; e < eend; e += 256) {
    int d = dst[e];
    if (d >= lo && d < hi) {
      int p = atomicAdd(&cursor[d], 1);
      nbr[row_ptr[d] + p] = src[e];  // order within row nondeterministic; max is invariant
    }
  }
}

// ---------------- weight prep: f32 -> bf16 hi/lo ----------------

__global__ __launch_bounds__(256) void k_prep_w(const float* __restrict__ Wl,
                                                const float* __restrict__ Wr,
                                                short* __restrict__ wb) {
  int idx = blockIdx.x * 256 + threadIdx.x;
  if (idx >= 7 * 2 * 16384) return;
  int li = idx / 32768;
  int rem = idx % 32768;
  int seg = rem / 16384;
  int ok = rem % 16384;
  float v = seg ? Wr[li * 16384 + ok] : Wl[li * 16384 + ok];
  short hi = bf16_rne(v);
  short lo = bf16_rne(v - bf16_f(hi));
  short* base = wb + (size_t)li * 65536 + seg * 32768;
  base[ok] = hi;
  base[16384 + ok] = lo;
}

// ---------------- fused hidden layer: 512-thread, 32-node tile, 8-deep gather ----------------
// hout = leaky( (max_{s in N(n)} hin[s]) @ Wl^T + bl + hin @ Wr^T )

__global__ __launch_bounds__(512, 8) void k_layer_fused(const float* __restrict__ hin,
                                                        const int* __restrict__ row_ptr,
                                                        const int* __restrict__ nbr,
                                                        const short* __restrict__ wbl,
                                                        const float* __restrict__ bl,
                                                        float* __restrict__ hout) {
  // LDS: 0=agg hi, 1=agg lo, 2=hin hi, 3=hin lo; each 32 rows x 128 k bf16 (8KB)
  // XOR swizzle on byte offsets: off ^= (row&7)<<4 (write and read)
  __shared__ __align__(16) char smem[4 * 8192];
  const int t = threadIdx.x;
  const int base = blockIdx.x * 32;

  // --- stage hin tile (root branch): one 8-float chunk per thread ---
  {
    char* dhi = smem + 2 * 8192;
    char* dlo = smem + 3 * 8192;
    int row = t >> 4;             // 32 rows x 16 chunks = 512
    int kc = (t & 15) * 8;
    const float4* g = (const float4*)(hin + (size_t)(base + row) * NFE + kc);
    float4 v0 = g[0], v1 = g[1];
    float f[8] = {v0.x, v0.y, v0.z, v0.w, v1.x, v1.y, v1.z, v1.w};
    s16x8 hv, lv;
#pragma unroll
    for (int j = 0; j < 8; ++j) {
      short h = bf16_rne(f[j]);
      hv[j] = h;
      lv[j] = bf16_rne(f[j] - bf16_f(h));
    }
    int off = row * 256 + kc * 2;
    off ^= (row & 7) << 4;
    *(s16x8*)(dhi + off) = hv;
    *(s16x8*)(dlo + off) = lv;
  }

  // --- gather-max into the A tile: 16 groups of 32 lanes, 2 rows each, 8-deep MLP ---
  {
    char* ahi = smem;
    char* alo = smem + 8192;
    const int grp = t >> 5;        // 0..15
    const int lg = t & 31;
    const int c4 = lg << 2;        // 4 contiguous channels
    const float NI = __int_as_float(0xFF800000);
#pragma unroll
    for (int ni = 0; ni < 2; ++ni) {
      const int r = grp * 2 + ni;  // in-block row
      const int n = base + r;
      const int start = row_ptr[n], end = row_ptr[n + 1];
      float4 acc = make_float4(NI, NI, NI, NI);
      int j = start;
      for (; j + 8 <= end; j += 8) {
        int s0 = nbr[j],     s1 = nbr[j + 1], s2 = nbr[j + 2], s3 = nbr[j + 3];
        int s4 = nbr[j + 4], s5 = nbr[j + 5], s6 = nbr[j + 6], s7 = nbr[j + 7];
        float4 v0 = *(const float4*)(hin + (size_t)s0 * NFE + c4);
        float4 v1 = *(const float4*)(hin + (size_t)s1 * NFE + c4);
        float4 v2 = *(const float4*)(hin + (size_t)s2 * NFE + c4);
        float4 v3 = *(const float4*)(hin + (size_t)s3 * NFE + c4);
        float4 v4 = *(const float4*)(hin + (size_t)s4 * NFE + c4);
        float4 v5 = *(const float4*)(hin + (size_t)s5 * NFE + c4);
        float4 v6 = *(const float4*)(hin + (size_t)s6 * NFE + c4);
        float4 v7 = *(const float4*)(hin + (size_t)s7 * NFE + c4);
        float4 m01 = fmax4(v0, v1), m23 = fmax4(v2, v3);
        float4 m45 = fmax4(v4, v5), m67 = fmax4(v6, v7);
        acc = fmax4(acc, fmax4(fmax4(m01, m23), fmax4(m45, m67)));
      }
      for (; j + 4 <= end; j += 4) {
        int s0 = nbr[j], s1 = nbr[j + 1], s2 = nbr[j + 2], s3 = nbr[j + 3];
        float4 v0 = *(const float4*)(hin + (size_t)s0 * NFE + c4);
        float4 v1 = *(const float4*)(hin + (size_t)s1 * NFE + c4);
        float4 v2 = *(const float4*)(hin + (size_t)s2 * NFE + c4);
        float4 v3 = *(const float4*)(hin + (size_t)s3 * NFE + c4);
        acc = fmax4(acc, fmax4(fmax4(v0, v1), fmax4(v2, v3)));
      }
      for (; j < end; ++j) {
        int s = nbr[j];
        acc = fmax4(acc, *(const float4*)(hin + (size_t)s * NFE + c4));
      }
      if (start == end) acc = make_float4(0.f, 0.f, 0.f, 0.f);
      float f[4] = {acc.x, acc.y, acc.z, acc.w};
      s16x4 hv, lv;
#pragma unroll
      for (int q = 0; q < 4; ++q) {
        short h = bf16_rne(f[q]);
        hv[q] = h;
        lv[q] = bf16_rne(f[q] - bf16_f(h));
      }
      int off = r * 256 + c4 * 2;
      off ^= (r & 7) << 4;
      *(s16x4*)(ahi + off) = hv;
      *(s16x4*)(alo + off) = lv;
    }
  }
  __syncthreads();

  // --- split-bf16 MFMA: Ahi*Whi + Ahi*Wlo + Alo*Whi per branch ---
  const int w = t >> 6;        // wave id 0..7: cols 16w..16w+15
  const int l = t & 63;
  const int lr = l & 15;
  const int lk = (l >> 4) * 8;

  f32x4 acc[2] = {};           // [row tile]

#pragma unroll
  for (int seg = 0; seg < 2; ++seg) {
    const char* ahi = smem + (seg * 2 + 0) * 8192;
    const char* alo = smem + (seg * 2 + 1) * 8192;
    const short* bhb = wbl + seg * 32768;
    const short* blb = wbl + seg * 32768 + 16384;
#pragma unroll
    for (int ks = 0; ks < 4; ++ks) {
      const int k0 = ks * 32;
      int offa0 = (lr) * 256 + (k0 + lk) * 2;      offa0 ^= ((lr) & 7) << 4;
      int offa1 = (16 + lr) * 256 + (k0 + lk) * 2; offa1 ^= ((16 + lr) & 7) << 4;
      s16x8 ah0 = *(const s16x8*)(ahi + offa0);
      s16x8 ah1 = *(const s16x8*)(ahi + offa1);
      s16x8 al0 = *(const s16x8*)(alo + offa0);
      s16x8 al1 = *(const s16x8*)(alo + offa1);
      const int col = w * 16 + lr;
      const s16x8 bh = *(const s16x8*)(bhb + col * 128 + k0 + lk);
      const s16x8 bl_ = *(const s16x8*)(blb + col * 128 + k0 + lk);
      acc[0] = __builtin_amdgcn_mfma_f32_16x16x32_bf16(ah0, bh, acc[0], 0, 0, 0);
      acc[1] = __builtin_amdgcn_mfma_f32_16x16x32_bf16(ah1, bh, acc[1], 0, 0, 0);
      acc[0] = __builtin_amdgcn_mfma_f32_16x16x32_bf16(ah0, bl_, acc[0], 0, 0, 0);
      acc[1] = __builtin_amdgcn_mfma_f32_16x16x32_bf16(ah1, bl_, acc[1], 0, 0, 0);
      acc[0] = __builtin_amdgcn_mfma_f32_16x16x32_bf16(al0, bh, acc[0], 0, 0, 0);
      acc[1] = __builtin_amdgcn_mfma_f32_16x16x32_bf16(al1, bh, acc[1], 0, 0, 0);
    }
  }

  // epilogue: bias + leaky; C layout: col = lane&15, row = (lane>>4)*4 + reg
  const float bias0 = bl[w * 16 + lr];
#pragma unroll
  for (int rt = 0; rt < 2; ++rt) {
#pragma unroll
    for (int r = 0; r < 4; ++r) {
      int node = base + 16 * rt + (l >> 4) * 4 + r;
      float* o = hout + (size_t)node * NFE + w * 16;
      o[lr] = leaky(acc[rt][r] + bias0);
    }
  }
}

// ---------------- fused output layer: gather-max + tiny GEMV + tanh, 8-deep ----------------

__global__ __launch_bounds__(256) void k_final_fused(const float* __restrict__ h,
                                                     const int* __restrict__ row_ptr,
                                                     const int* __restrict__ nbr,
                                                     const float* __restrict__ Wlo,
                                                     const float* __restrict__ blo,
                                                     const float* __restrict__ Wro,
                                                     float* __restrict__ out) {
  const int wave = threadIdx.x >> 6;
  const int lane = threadIdx.x & 63;
  const int n = blockIdx.x * 4 + wave;
  if (n >= NN) return;
  const int c2 = lane * 2;
  const int start = row_ptr[n], end = row_ptr[n + 1];
  const float NI = __int_as_float(0xFF800000);
  float ax = NI, ay = NI;
  int j = start;
  for (; j + 8 <= end; j += 8) {
    int s0 = nbr[j],     s1 = nbr[j + 1], s2 = nbr[j + 2], s3 = nbr[j + 3];
    int s4 = nbr[j + 4], s5 = nbr[j + 5], s6 = nbr[j + 6], s7 = nbr[j + 7];
    float2 v0 = *(const float2*)(h + (size_t)s0 * NFE + c2);
    float2 v1 = *(const float2*)(h + (size_t)s1 * NFE + c2);
    float2 v2 = *(const float2*)(h + (size_t)s2 * NFE + c2);
    float2 v3 = *(const float2*)(h + (size_t)s3 * NFE + c2);
    float2 v4 = *(const float2*)(h + (size_t)s4 * NFE + c2);
    float2 v5 = *(const float2*)(h + (size_t)s5 * NFE + c2);
    float2 v6 = *(const float2*)(h + (size_t)s6 * NFE + c2);
    float2 v7 = *(const float2*)(h + (size_t)s7 * NFE + c2);
    ax = fmaxf(ax, fmaxf(fmaxf(fmaxf(v0.x, v1.x), fmaxf(v2.x, v3.x)),
                         fmaxf(fmaxf(v4.x, v5.x), fmaxf(v6.x, v7.x))));
    ay = fmaxf(ay, fmaxf(fmaxf(fmaxf(v0.y, v1.y), fmaxf(v2.y, v3.y)),
                         fmaxf(fmaxf(v4.y, v5.y), fmaxf(v6.y, v7.y))));
  }
  for (; j + 4 <= end; j += 4) {
    int s0 = nbr[j], s1 = nbr[j + 1], s2 = nbr[j + 2], s3 = nbr[j + 3];
    float2 v0 = *(const float2*)(h + (size_t)s0 * NFE + c2);
    float2 v1 = *(const float2*)(h + (size_t)s1 * NFE + c2);
    float2 v2 = *(const float2*)(h + (size_t)s2 * NFE + c2);
    float2 v3 = *(const float2*)(h + (size_t)s3 * NFE + c2);
    ax = fmaxf(ax, fmaxf(fmaxf(v0.x, v1.x), fmaxf(v2.x, v3.x)));
    ay = fmaxf(ay, fmaxf(fmaxf(v0.y, v1.y), fmaxf(v2.y, v3.y)));
  }
  for (; j < end; ++j) {
    float2 v = *(const float2*)(h + (size_t)nbr[j] * NFE + c2);
    ax = fmaxf(ax, v.x);
    ay = fmaxf(ay, v.y);
  }
  if (start == end) { ax = 0.f; ay = 0.f; }
  const float2 hv = *(const float2*)(h + (size_t)n * NFE + c2);
  float p[3];
#pragma unroll
  for (int o = 0; o < 3; ++o) {
    const float2 wl = *(const float2*)(Wlo + o * NFE + c2);
    const float2 wr = *(const float2*)(Wro + o * NFE + c2);
    p[o] = ax * wl.x + ay * wl.y + hv.x * wr.x + hv.y * wr.y;
#pragma unroll
    for (int off = 32; off; off >>= 1) p[o] += __shfl_down(p[o], off, 64);
  }
  if (lane == 0) {
#pragma unroll
    for (int o = 0; o < 3; ++o)
      out[(size_t)n * 3 + o] = tanhf(p[o] + blo[o]) * 0.5f;
  }
}

// ---------------- launch ----------------

extern "C" void kernel_launch(void* const* d_in, const int* in_sizes, int n_in,
                              void* d_out, int out_size, void* d_ws, size_t ws_size,
                              hipStream_t stream) {
  const float* x   = (const float*)d_in[0];
  const int*   ei  = (const int*)d_in[1];
  const float* Wl  = (const float*)d_in[2];
  const float* bl  = (const float*)d_in[3];
  const float* Wr  = (const float*)d_in[4];
  const float* Wlo = (const float*)d_in[5];
  const float* blo = (const float*)d_in[6];
  const float* Wro = (const float*)d_in[7];
  float* out = (float*)d_out;

  const int* src = ei;
  const int* dst = ei + NE;

  char* ws = (char*)d_ws;
  size_t off = 0;
  auto alloc = [&](size_t bytes) { void* p = ws + off; off = (off + bytes + 255) & ~(size_t)255; return p; };
  int* counts  = (int*)alloc(sizeof(int) * NN);
  int* cursor  = (int*)alloc(sizeof(int) * NN);
  int* row_ptr = (int*)alloc(sizeof(int) * (NN + 1));
  int* nbr     = (int*)alloc(sizeof(int) * NE);
  int* bsum    = (int*)alloc(sizeof(int) * 128);
  int* boff    = (int*)alloc(sizeof(int) * 128);
  short* wb    = (short*)alloc(sizeof(short) * 7 * 65536);
  const size_t hbytes = (size_t)NN * NFE * sizeof(float);
  float* hA  = (float*)alloc(hbytes);
  float* hB  = (float*)alloc(hbytes);

  k_prep_w<<<(7 * 32768 + 255) / 256, 256, 0, stream>>>(Wl, Wr, wb);
  k_zero_i32<<<(NN + 255) / 256, 256, 0, stream>>>(counts, NN);
  k_hist_binned<<<8 * FILL_NCHUNK, 256, 0, stream>>>(dst, counts);
  k_scan_sum<<<SCAN_NB, 256, 0, stream>>>(counts, bsum);
  k_scan_top<<<1, 128, 0, stream>>>(bsum, boff);
  k_scan_blk<<<SCAN_NB, 256, 0, stream>>>(counts, boff, row_ptr, cursor);
  k_fill_binned<<<8 * FILL_NCHUNK, 256, 0, stream>>>(src, dst, row_ptr, cursor, nbr);

  const float* hin = x;
  float* bufs[2] = {hA, hB};
  for (int i = 0; i < 7; ++i) {
    float* hout = bufs[i & 1];
    k_layer_fused<<<NN / 32, 512, 0, stream>>>(hin, row_ptr, nbr,
                                               wb + (size_t)i * 65536,
                                               bl + (size_t)i * NFE, hout);
    hin = hout;
  }

  k_final_fused<<<(NN + 3) / 4, 256, 0, stream>>>(hin, row_ptr, nbr, Wlo, blo, Wro, out);
}

// Round 13
// 1200.001 us; speedup vs baseline: 1.2743x; 1.0466x over previous
//
#include <hip/hip_runtime.h>
#include <hip/hip_bf16.h>
#include <math.h>

#define NN 100000
#define NE 1600000
#define NFE 128
#define SCAN_NB 98        // ceil(NN/1024)
#define FILL_CHUNK 8192
#define FILL_NCHUNK 196   // ceil(NE/FILL_CHUNK)
#define FILL_BUCKET 12500 // NN/8 exactly

using f32x4 = __attribute__((ext_vector_type(4))) float;
using s16x8 = __attribute__((ext_vector_type(8))) short;
using s16x4 = __attribute__((ext_vector_type(4))) short;

__device__ __forceinline__ short bf16_rne(float x) {
  unsigned u = __float_as_uint(x);
  unsigned r = u + 0x7FFFu + ((u >> 16) & 1u);
  return (short)(r >> 16);
}
__device__ __forceinline__ float bf16_f(short s) {
  return __uint_as_float(((unsigned)(unsigned short)s) << 16);
}
__device__ __forceinline__ float leaky(float v) {
  return v >= 0.0f ? v : 0.02f * v;
}
__device__ __forceinline__ float4 fmax4(float4 a, float4 b) {
  return make_float4(fmaxf(a.x, b.x), fmaxf(a.y, b.y), fmaxf(a.z, b.z), fmaxf(a.w, b.w));
}

// ---------------- CSR build (once per call) ----------------

__global__ __launch_bounds__(256) void k_zero_i32(int* __restrict__ p, int n) {
  int i = blockIdx.x * blockDim.x + threadIdx.x;
  if (i < n) p[i] = 0;
}

__global__ __launch_bounds__(256) void k_hist_binned(const int* __restrict__ dst,
                                                     int* __restrict__ counts) {
  const int x = blockIdx.x & 7;
  const int k = blockIdx.x >> 3;
  const int lo = x * FILL_BUCKET, hi = lo + FILL_BUCKET;
  const int eend = min(NE, (k + 1) * FILL_CHUNK);
  for (int e = k * FILL_CHUNK + threadIdx.x; e < eend; e += 256) {
    int d = dst[e];
    if (d >= lo && d < hi) atomicAdd(&counts[d], 1);
  }
}

__global__ __launch_bounds__(256) void k_scan_sum(const int* __restrict__ counts,
                                                  int* __restrict__ bsum) {
  const int t = threadIdx.x;
  const int base = blockIdx.x * 1024 + t * 4;
  int4 c = make_int4(0, 0, 0, 0);
  if (base + 3 < NN) c = *(const int4*)(counts + base);
  else {
    if (base + 0 < NN) c.x = counts[base + 0];
    if (base + 1 < NN) c.y = counts[base + 1];
    if (base + 2 < NN) c.z = counts[base + 2];
  }
  int s = c.x + c.y + c.z + c.w;
#pragma unroll
  for (int off = 32; off; off >>= 1) s += __shfl_down(s, off, 64);
  __shared__ int ws[4];
  if ((t & 63) == 0) ws[t >> 6] = s;
  __syncthreads();
  if (t == 0) bsum[blockIdx.x] = ws[0] + ws[1] + ws[2] + ws[3];
}

__global__ __launch_bounds__(128) void k_scan_top(const int* __restrict__ bsum,
                                                  int* __restrict__ boff) {
  __shared__ int v[128];
  const int t = threadIdx.x;
  int mine = (t < SCAN_NB) ? bsum[t] : 0;
  v[t] = mine;
  __syncthreads();
  for (int off = 1; off < 128; off <<= 1) {
    int u = (t >= off) ? v[t - off] : 0;
    __syncthreads();
    v[t] += u;
    __syncthreads();
  }
  if (t < SCAN_NB) boff[t] = v[t] - mine;  // exclusive
}

__global__ __launch_bounds__(256) void k_scan_blk(const int* __restrict__ counts,
                                                  const int* __restrict__ boff,
                                                  int* __restrict__ row_ptr,
                                                  int* __restrict__ cursor) {
  __shared__ int part[256];
  const int t = threadIdx.x;
  const int base = blockIdx.x * 1024 + t * 4;
  int4 c = make_int4(0, 0, 0, 0);
  if (base + 3 < NN) c = *(const int4*)(counts + base);
  else {
    if (base + 0 < NN) c.x = counts[base + 0];
    if (base + 1 < NN) c.y = counts[base + 1];
    if (base + 2 < NN) c.z = counts[base + 2];
  }
  const int s = c.x + c.y + c.z + c.w;
  part[t] = s;
  __syncthreads();
  for (int off = 1; off < 256; off <<= 1) {
    int u = (t >= off) ? part[t - off] : 0;
    __syncthreads();
    part[t] += u;
    __syncthreads();
  }
  int excl = boff[blockIdx.x] + part[t] - s;
  int4 r;
  r.x = excl;
  r.y = r.x + c.x;
  r.z = r.y + c.y;
  r.w = r.z + c.z;
  const int4 z = make_int4(0, 0, 0, 0);
  if (base + 3 < NN) {
    *(int4*)(row_ptr + base) = r;
    *(int4*)(cursor + base) = z;
  } else {
    if (base + 0 < NN) { row_ptr[base + 0] = r.x; cursor[base + 0] = 0; }
    if (base + 1 < NN) { row_ptr[base + 1] = r.y; cursor[base + 1] = 0; }
    if (base + 2 < NN) { row_ptr[base + 2] = r.z; cursor[base + 2] = 0; }
  }
  if (blockIdx.x == 0 && t == 0) row_ptr[NN] = NE;
}

__global__ __launch_bounds__(256) void k_fill_binned(const int* __restrict__ src,
                                                     const int* __restrict__ dst,
                                                     const int* __restrict__ row_ptr,
                                                     int* __restrict__ cursor,
                                                     int* __restrict__ nbr) {
  const int x = blockIdx.x & 7;
  const int k = blockIdx.x >> 3;
  const int lo = x * FILL_BUCKET, hi = lo + FILL_BUCKET;
  const int eend = min(NE, (k + 1) * FILL_CHUNK);
  for (int e = k * FILL_CHUNK + threadIdx.x; e < eend; e += 256) {
    int d = dst[e];
    if (d >= lo && d < hi) {
      int p = atomicAdd(&cursor[d], 1);
      nbr[row_ptr[d] + p] = src[e];  // order within row nondeterministic; max is invariant
    }
  }
}

// ---------------- weight prep: f32 -> bf16 hi/lo ----------------

__global__ __launch_bounds__(256) void k_prep_w(const float* __restrict__ Wl,
                                                const float* __restrict__ Wr,
                                                short* __restrict__ wb) {
  int idx = blockIdx.x * 256 + threadIdx.x;
  if (idx >= 7 * 2 * 16384) return;
  int li = idx / 32768;
  int rem = idx % 32768;
  int seg = rem / 16384;
  int ok = rem % 16384;
  float v = seg ? Wr[li * 16384 + ok] : Wl[li * 16384 + ok];
  short hi = bf16_rne(v);
  short lo = bf16_rne(v - bf16_f(hi));
  short* base = wb + (size_t)li * 65536 + seg * 32768;
  base[ok] = hi;
  base[16384 + ok] = lo;
}

// ---------------- fused hidden layer: 512-thread, 32-node tile ----------------
// hout = leaky( (max_{s in N(n)} hin[s]) @ Wl^T + bl + hin @ Wr^T )
// Gather loop: uniform clamped 8-batches; duplicates are idempotent under max
// and L1-hot (same line as previous load) -> no serial tail, no masking.

__global__ __launch_bounds__(512, 8) void k_layer_fused(const float* __restrict__ hin,
                                                        const int* __restrict__ row_ptr,
                                                        const int* __restrict__ nbr,
                                                        const short* __restrict__ wbl,
                                                        const float* __restrict__ bl,
                                                        float* __restrict__ hout) {
  // LDS: 0=agg hi, 1=agg lo, 2=hin hi, 3=hin lo; each 32 rows x 128 k bf16 (8KB)
  // XOR swizzle on byte offsets: off ^= (row&7)<<4 (write and read)
  __shared__ __align__(16) char smem[4 * 8192];
  const int t = threadIdx.x;
  const int base = blockIdx.x * 32;

  // --- stage hin tile (root branch): one 8-float chunk per thread ---
  {
    char* dhi = smem + 2 * 8192;
    char* dlo = smem + 3 * 8192;
    int row = t >> 4;             // 32 rows x 16 chunks = 512
    int kc = (t & 15) * 8;
    const float4* g = (const float4*)(hin + (size_t)(base + row) * NFE + kc);
    float4 v0 = g[0], v1 = g[1];
    float f[8] = {v0.x, v0.y, v0.z, v0.w, v1.x, v1.y, v1.z, v1.w};
    s16x8 hv, lv;
#pragma unroll
    for (int j = 0; j < 8; ++j) {
      short h = bf16_rne(f[j]);
      hv[j] = h;
      lv[j] = bf16_rne(f[j] - bf16_f(h));
    }
    int off = row * 256 + kc * 2;
    off ^= (row & 7) << 4;
    *(s16x8*)(dhi + off) = hv;
    *(s16x8*)(dlo + off) = lv;
  }

  // --- gather-max into the A tile: 16 groups of 32 lanes, 2 rows each ---
  {
    char* ahi = smem;
    char* alo = smem + 8192;
    const int grp = t >> 5;        // 0..15
    const int lg = t & 31;
    const int c4 = lg << 2;        // 4 contiguous channels
    const float NI = __int_as_float(0xFF800000);
#pragma unroll
    for (int ni = 0; ni < 2; ++ni) {
      const int r = grp * 2 + ni;  // in-block row
      const int n = base + r;
      const int start = row_ptr[n], end = row_ptr[n + 1];
      float4 acc = make_float4(NI, NI, NI, NI);
      const int last = end - 1;
      for (int j = start; j < end; j += 8) {
        int i0 = min(j + 0, last), i1 = min(j + 1, last);
        int i2 = min(j + 2, last), i3 = min(j + 3, last);
        int i4 = min(j + 4, last), i5 = min(j + 5, last);
        int i6 = min(j + 6, last), i7 = min(j + 7, last);
        int s0 = nbr[i0], s1 = nbr[i1], s2 = nbr[i2], s3 = nbr[i3];
        int s4 = nbr[i4], s5 = nbr[i5], s6 = nbr[i6], s7 = nbr[i7];
        float4 v0 = *(const float4*)(hin + (size_t)s0 * NFE + c4);
        float4 v1 = *(const float4*)(hin + (size_t)s1 * NFE + c4);
        float4 v2 = *(const float4*)(hin + (size_t)s2 * NFE + c4);
        float4 v3 = *(const float4*)(hin + (size_t)s3 * NFE + c4);
        float4 v4 = *(const float4*)(hin + (size_t)s4 * NFE + c4);
        float4 v5 = *(const float4*)(hin + (size_t)s5 * NFE + c4);
        float4 v6 = *(const float4*)(hin + (size_t)s6 * NFE + c4);
        float4 v7 = *(const float4*)(hin + (size_t)s7 * NFE + c4);
        float4 m01 = fmax4(v0, v1), m23 = fmax4(v2, v3);
        float4 m45 = fmax4(v4, v5), m67 = fmax4(v6, v7);
        acc = fmax4(acc, fmax4(fmax4(m01, m23), fmax4(m45, m67)));
      }
      if (start == end) acc = make_float4(0.f, 0.f, 0.f, 0.f);
      float f[4] = {acc.x, acc.y, acc.z, acc.w};
      s16x4 hv, lv;
#pragma unroll
      for (int q = 0; q < 4; ++q) {
        short h = bf16_rne(f[q]);
        hv[q] = h;
        lv[q] = bf16_rne(f[q] - bf16_f(h));
      }
      int off = r * 256 + c4 * 2;
      off ^= (r & 7) << 4;
      *(s16x4*)(ahi + off) = hv;
      *(s16x4*)(alo + off) = lv;
    }
  }
  __syncthreads();

  // --- split-bf16 MFMA: Ahi*Whi + Ahi*Wlo + Alo*Whi per branch ---
  const int w = t >> 6;        // wave id 0..7: cols 16w..16w+15
  const int l = t & 63;
  const int lr = l & 15;
  const int lk = (l >> 4) * 8;

  f32x4 acc[2] = {};           // [row tile]

#pragma unroll
  for (int seg = 0; seg < 2; ++seg) {
    const char* ahi = smem + (seg * 2 + 0) * 8192;
    const char* alo = smem + (seg * 2 + 1) * 8192;
    const short* bhb = wbl + seg * 32768;
    const short* blb = wbl + seg * 32768 + 16384;
#pragma unroll
    for (int ks = 0; ks < 4; ++ks) {
      const int k0 = ks * 32;
      int offa0 = (lr) * 256 + (k0 + lk) * 2;      offa0 ^= ((lr) & 7) << 4;
      int offa1 = (16 + lr) * 256 + (k0 + lk) * 2; offa1 ^= ((16 + lr) & 7) << 4;
      s16x8 ah0 = *(const s16x8*)(ahi + offa0);
      s16x8 ah1 = *(const s16x8*)(ahi + offa1);
      s16x8 al0 = *(const s16x8*)(alo + offa0);
      s16x8 al1 = *(const s16x8*)(alo + offa1);
      const int col = w * 16 + lr;
      const s16x8 bh = *(const s16x8*)(bhb + col * 128 + k0 + lk);
      const s16x8 bl_ = *(const s16x8*)(blb + col * 128 + k0 + lk);
      acc[0] = __builtin_amdgcn_mfma_f32_16x16x32_bf16(ah0, bh, acc[0], 0, 0, 0);
      acc[1] = __builtin_amdgcn_mfma_f32_16x16x32_bf16(ah1, bh, acc[1], 0, 0, 0);
      acc[0] = __builtin_amdgcn_mfma_f32_16x16x32_bf16(ah0, bl_, acc[0], 0, 0, 0);
      acc[1] = __builtin_amdgcn_mfma_f32_16x16x32_bf16(ah1, bl_, acc[1], 0, 0, 0);
      acc[0] = __builtin_amdgcn_mfma_f32_16x16x32_bf16(al0, bh, acc[0], 0, 0, 0);
      acc[1] = __builtin_amdgcn_mfma_f32_16x16x32_bf16(al1, bh, acc[1], 0, 0, 0);
    }
  }

  // epilogue: bias + leaky; C layout: col = lane&15, row = (lane>>4)*4 + reg
  const float bias0 = bl[w * 16 + lr];
#pragma unroll
  for (int rt = 0; rt < 2; ++rt) {
#pragma unroll
    for (int r = 0; r < 4; ++r) {
      int node = base + 16 * rt + (l >> 4) * 4 + r;
      float* o = hout + (size_t)node * NFE + w * 16;
      o[lr] = leaky(acc[rt][r] + bias0);
    }
  }
}

// ---------------- fused output layer: clamped 8-deep gather + GEMV + tanh ----------------

__global__ __launch_bounds__(256) void k_final_fused(const float* __restrict__ h,
                                                     const int* __restrict__ row_ptr,
                                                     const int* __restrict__ nbr,
                                                     const float* __restrict__ Wlo,
                                                     const float* __restrict__ blo,
                                                     const float* __restrict__ Wro,
                                                     float* __restrict__ out) {
  const int wave = threadIdx.x >> 6;
  const int lane = threadIdx.x & 63;
  const int n = blockIdx.x * 4 + wave;
  if (n >= NN) return;
  const int c2 = lane * 2;
  const int start = row_ptr[n], end = row_ptr[n + 1];
  const float NI = __int_as_float(0xFF800000);
  float ax = NI, ay = NI;
  const int last = end - 1;
  for (int j = start; j < end; j += 8) {
    int i0 = min(j + 0, last), i1 = min(j + 1, last);
    int i2 = min(j + 2, last), i3 = min(j + 3, last);
    int i4 = min(j + 4, last), i5 = min(j + 5, last);
    int i6 = min(j + 6, last), i7 = min(j + 7, last);
    int s0 = nbr[i0], s1 = nbr[i1], s2 = nbr[i2], s3 = nbr[i3];
    int s4 = nbr[i4], s5 = nbr[i5], s6 = nbr[i6], s7 = nbr[i7];
    float2 v0 = *(const float2*)(h + (size_t)s0 * NFE + c2);
    float2 v1 = *(const float2*)(h + (size_t)s1 * NFE + c2);
    float2 v2 = *(const float2*)(h + (size_t)s2 * NFE + c2);
    float2 v3 = *(const float2*)(h + (size_t)s3 * NFE + c2);
    float2 v4 = *(const float2*)(h + (size_t)s4 * NFE + c2);
    float2 v5 = *(const float2*)(h + (size_t)s5 * NFE + c2);
    float2 v6 = *(const float2*)(h + (size_t)s6 * NFE + c2);
    float2 v7 = *(const float2*)(h + (size_t)s7 * NFE + c2);
    ax = fmaxf(ax, fmaxf(fmaxf(fmaxf(v0.x, v1.x), fmaxf(v2.x, v3.x)),
                         fmaxf(fmaxf(v4.x, v5.x), fmaxf(v6.x, v7.x))));
    ay = fmaxf(ay, fmaxf(fmaxf(fmaxf(v0.y, v1.y), fmaxf(v2.y, v3.y)),
                         fmaxf(fmaxf(v4.y, v5.y), fmaxf(v6.y, v7.y))));
  }
  if (start == end) { ax = 0.f; ay = 0.f; }
  const float2 hv = *(const float2*)(h + (size_t)n * NFE + c2);
  float p[3];
#pragma unroll
  for (int o = 0; o < 3; ++o) {
    const float2 wl = *(const float2*)(Wlo + o * NFE + c2);
    const float2 wr = *(const float2*)(Wro + o * NFE + c2);
    p[o] = ax * wl.x + ay * wl.y + hv.x * wr.x + hv.y * wr.y;
#pragma unroll
    for (int off = 32; off; off >>= 1) p[o] += __shfl_down(p[o], off, 64);
  }
  if (lane == 0) {
#pragma unroll
    for (int o = 0; o < 3; ++o)
      out[(size_t)n * 3 + o] = tanhf(p[o] + blo[o]) * 0.5f;
  }
}

// ---------------- launch ----------------

extern "C" void kernel_launch(void* const* d_in, const int* in_sizes, int n_in,
                              void* d_out, int out_size, void* d_ws, size_t ws_size,
                              hipStream_t stream) {
  const float* x   = (const float*)d_in[0];
  const int*   ei  = (const int*)d_in[1];
  const float* Wl  = (const float*)d_in[2];
  const float* bl  = (const float*)d_in[3];
  const float* Wr  = (const float*)d_in[4];
  const float* Wlo = (const float*)d_in[5];
  const float* blo = (const float*)d_in[6];
  const float* Wro = (const float*)d_in[7];
  float* out = (float*)d_out;

  const int* src = ei;
  const int* dst = ei + NE;

  char* ws = (char*)d_ws;
  size_t off = 0;
  auto alloc = [&](size_t bytes) { void* p = ws + off; off = (off + bytes + 255) & ~(size_t)255; return p; };
  int* counts  = (int*)alloc(sizeof(int) * NN);
  int* cursor  = (int*)alloc(sizeof(int) * NN);
  int* row_ptr = (int*)alloc(sizeof(int) * (NN + 1));
  int* nbr     = (int*)alloc(sizeof(int) * NE);
  int* bsum    = (int*)alloc(sizeof(int) * 128);
  int* boff    = (int*)alloc(sizeof(int) * 128);
  short* wb    = (short*)alloc(sizeof(short) * 7 * 65536);
  const size_t hbytes = (size_t)NN * NFE * sizeof(float);
  float* hA  = (float*)alloc(hbytes);
  float* hB  = (float*)alloc(hbytes);

  k_prep_w<<<(7 * 32768 + 255) / 256, 256, 0, stream>>>(Wl, Wr, wb);
  k_zero_i32<<<(NN + 255) / 256, 256, 0, stream>>>(counts, NN);
  k_hist_binned<<<8 * FILL_NCHUNK, 256, 0, stream>>>(dst, counts);
  k_scan_sum<<<SCAN_NB, 256, 0, stream>>>(counts, bsum);
  k_scan_top<<<1, 128, 0, stream>>>(bsum, boff);
  k_scan_blk<<<SCAN_NB, 256, 0, stream>>>(counts, boff, row_ptr, cursor);
  k_fill_binned<<<8 * FILL_NCHUNK, 256, 0, stream>>>(src, dst, row_ptr, cursor, nbr);

  const float* hin = x;
  float* bufs[2] = {hA, hB};
  for (int i = 0; i < 7; ++i) {
    float* hout = bufs[i & 1];
    k_layer_fused<<<NN / 32, 512, 0, stream>>>(hin, row_ptr, nbr,
                                               wb + (size_t)i * 65536,
                                               bl + (size_t)i * NFE, hout);
    hin = hout;
  }

  k_final_fused<<<(NN + 3) / 4, 256, 0, stream>>>(hin, row_ptr, nbr, Wlo, blo, Wro, out);
}